// Round 5
// baseline (297.520 us; speedup 1.0000x reference)
//
#include <hip/hip_runtime.h>
#include <stdint.h>
#include <math.h>

typedef unsigned short u16;
typedef short bf16x8 __attribute__((ext_vector_type(8)));
typedef unsigned short u16x8 __attribute__((ext_vector_type(8)));
typedef unsigned short u16x4 __attribute__((ext_vector_type(4)));
typedef float f32x4 __attribute__((ext_vector_type(4)));

typedef __attribute__((address_space(1))) const void gvoid;
typedef __attribute__((address_space(3))) void lvoid;

#define LOG2E 1.4426950408889634f

__device__ __forceinline__ float bf2f(u16 u) {
  union { unsigned int i; float f; } v; v.i = ((unsigned int)u) << 16; return v.f;
}
__device__ __forceinline__ u16 f2bf(float f) {
  union { float ff; unsigned int i; } v; v.ff = f;
  unsigned int x = v.i;
  return (u16)((x + 0x7FFFu + ((x >> 16) & 1u)) >> 16);
}

// ---------------------------------------------------------------------------
// fp32 -> bf16 flat convert (n divisible by 2048 in practice; guarded anyway)
// ---------------------------------------------------------------------------
__global__ __launch_bounds__(256)
void cvt_f32_bf16(const float* __restrict__ src, u16* __restrict__ dst, long n)
{
  long i = ((long)blockIdx.x * 256 + threadIdx.x) * 8;
  if (i + 8 > n) return;
  f32x4 a = *(const f32x4*)&src[i];
  f32x4 b = *(const f32x4*)&src[i + 4];
  u16x8 o;
#pragma unroll
  for (int j = 0; j < 4; j++) { o[j] = f2bf(a[j]); o[4 + j] = f2bf(b[j]); }
  *(u16x8*)&dst[i] = o;
}

// ---------------------------------------------------------------------------
// Per-batch transpose+convert: VT[b][n][k] = (bf16)V[b][k][n]. 64x64 tiles.
// ---------------------------------------------------------------------------
__global__ __launch_bounds__(256)
void transcvt_v(const float* __restrict__ V, u16* __restrict__ VT, int S, int E)
{
  __shared__ u16 t[64][72];
  const int b = blockIdx.z;
  const float* Vb = V + (long)b * S * E;
  u16* VTb = VT + (long)b * S * E;
  const int k0 = blockIdx.x * 64, n0 = blockIdx.y * 64;
  const int tid = threadIdx.x;
#pragma unroll
  for (int p = 0; p < 2; p++) {
    int kk = p * 32 + (tid >> 3);
    int nn = (tid & 7) * 8;
    f32x4 a = *(const f32x4*)&Vb[(long)(k0 + kk) * E + n0 + nn];
    f32x4 c = *(const f32x4*)&Vb[(long)(k0 + kk) * E + n0 + nn + 4];
#pragma unroll
    for (int j = 0; j < 4; j++) { t[nn + j][kk] = f2bf(a[j]); t[nn + 4 + j][kk] = f2bf(c[j]); }
  }
  __syncthreads();
#pragma unroll
  for (int p = 0; p < 2; p++) {
    int nn = p * 32 + (tid >> 3);
    int kk = (tid & 7) * 8;
    u16x8 u;
#pragma unroll
    for (int j = 0; j < 8; j++) u[j] = t[nn][kk + j];
    *(u16x8*)&VTb[(long)(n0 + nn) * S + k0 + kk] = u;
  }
}

// ---------------------------------------------------------------------------
// FAST bf16 GEMM (BT layout), m97 structure + T3 minimum 2-phase pipeline:
//   C[g][n] = scale * sum_k A[g][k]*B[n][k] (+ mask fp32)
// 128x128 tile, BK=32, 4 waves, 4x4 16x16x32 bf16 MFMA accumulators.
// DOUBLE-BUFFERED LDS: STAGE(t+1) is issued BEFORE ds_read+MFMA of tile t;
// one __syncthreads() (implicit vmcnt(0)+lgkmcnt(0) drain) per K-step, AFTER
// the MFMA — so the staging loads fly during compute instead of draining
// cold. (T3 recipe; our grid gives only 1-2 blocks/CU so intra-block
// pipelining is the only latency hiding available.)
// ---------------------------------------------------------------------------
template<int HASMASK, int COUT>
__global__ __launch_bounds__(256, 3)
void gemm_bt_fast(const u16* __restrict__ A, int lda, long aRowOff,
                  const u16* __restrict__ B, int ldb, long bBatchStride,
                  void* __restrict__ Cp, int ldc, long cRowOff,
                  const float* __restrict__ maskf,
                  int K, float scale, long g0, int S)
{
  const int tid  = threadIdx.x;
  const int lane = tid & 63;
  const int wave = tid >> 6;
  const long gTile = g0 + (long)blockIdx.y * 128;
  const int  bidx  = (int)(gTile / S);
  const int  nTile = blockIdx.x * 128;

  __shared__ u16 As[2][128][32];   // double buffer, 8 KB each, linear rows
  __shared__ u16 Bs[2][128][32];

  const u16* Ab = A + (gTile - aRowOff) * (long)lda;
  const u16* Bb = B + (long)bidx * bBatchStride + (long)nTile * ldb;

  const int qm = (wave >> 1) * 64;
  const int qn = (wave & 1) * 64;
  const int lm  = lane & 15;          // m/n index within 16x16 fragment
  const int lk8 = (lane >> 4) * 8;    // u16 offset of k-slice within 32-col row

  // staging: wave covers chunks 2w..2w+1 of 1024 B; lane l writes LDS byte
  // chunk*1024 + l*16 -> row chunk*16 + l/4, col(u16) (l&3)*8.
  const int sr = lane >> 2;
  const int sc = (lane & 3) * 8;

  f32x4 acc[4][4];
#pragma unroll
  for (int i = 0; i < 4; i++)
#pragma unroll
    for (int j = 0; j < 4; j++) acc[i][j] = (f32x4){0.f, 0.f, 0.f, 0.f};

  auto STAGE = [&](int buf, int t) {
#pragma unroll
    for (int p = 0; p < 2; p++) {
      const int chunk = wave * 2 + p;        // 0..7, wave-uniform
      const int rr = chunk * 16 + sr;
      const int gc = t * 32 + sc;
      __builtin_amdgcn_global_load_lds(
          (gvoid*)&Ab[(long)rr * lda + gc],
          (lvoid*)((char*)&As[buf][0][0] + chunk * 1024),
          16, 0, 0);
      __builtin_amdgcn_global_load_lds(
          (gvoid*)&Bb[(long)rr * ldb + gc],
          (lvoid*)((char*)&Bs[buf][0][0] + chunk * 1024),
          16, 0, 0);
    }
  };

  auto COMPUTE = [&](int buf) {
    bf16x8 af[4], bfr[4];
#pragma unroll
    for (int rt = 0; rt < 4; rt++)
      af[rt] = *(const bf16x8*)&As[buf][qm + rt * 16 + lm][lk8];
#pragma unroll
    for (int ct = 0; ct < 4; ct++)
      bfr[ct] = *(const bf16x8*)&Bs[buf][qn + ct * 16 + lm][lk8];
#pragma unroll
    for (int rt = 0; rt < 4; rt++)
#pragma unroll
      for (int ct = 0; ct < 4; ct++)
        acc[rt][ct] = __builtin_amdgcn_mfma_f32_16x16x32_bf16(af[rt], bfr[ct], acc[rt][ct], 0, 0, 0);
  };

  const int nt = K >> 5;                // K/32 tiles
  STAGE(0, 0);
  __syncthreads();                      // drain prologue stage
  int cur = 0;
  for (int t = 0; t < nt - 1; t++) {
    STAGE(cur ^ 1, t + 1);              // issue next-tile loads FIRST
    COMPUTE(cur);                       // ds_read + MFMA overlap the loads
    __syncthreads();                    // single drain+publish per K-step
    cur ^= 1;
  }
  COMPUTE(cur);                         // last tile: no prefetch, no barrier

  // epilogue: C/D layout col = lane&15, row = (lane>>4)*4 + reg
  const int lr = (lane >> 4) * 4;
#pragma unroll
  for (int rt = 0; rt < 4; rt++) {
#pragma unroll
    for (int ct = 0; ct < 4; ct++) {
      long gr = gTile + qm + rt * 16 + lr;
      int  cc = nTile + qn + ct * 16 + lm;
#pragma unroll
      for (int i = 0; i < 4; i++) {
        float v = acc[rt][ct][i] * scale;
        if (HASMASK) v += maskf[(gr + i) * (long)ldc + cc];
        if (COUT == 0)
          ((u16*)Cp)[(gr + i - cRowOff) * (long)ldc + cc] = f2bf(v);
        else
          ((float*)Cp)[(gr + i - cRowOff) * (long)ldc + cc] = v;
      }
    }
  }
}

// ---------------------------------------------------------------------------
// GEMM (BT layout) — generic fallback (fp32 sources, no-workspace path).
// ---------------------------------------------------------------------------
template<int ASRC, int BSRC, int BMODE, int HASMASK, int COUT>
__global__ __launch_bounds__(256, 2)
void gemm_bt(const void* __restrict__ Ap, int lda, long aRowOff,
             const void* __restrict__ Bp, int ldb, long bBatchStride,
             void* __restrict__ Cp, int ldc, long cRowOff,
             const float* __restrict__ maskf,
             int K, float scale, long g0, int S)
{
  const int tid  = threadIdx.x;
  const int lane = tid & 63;
  const int wave = tid >> 6;
  const long gTile = g0 + (long)blockIdx.y * 128;
  const int  b     = (int)(gTile / S);
  const int  nTile = blockIdx.x * 128;

  __shared__ u16 As[128][40];   // +8 pad keeps 16B row alignment
  __shared__ u16 Bs[128][40];

  const int qm = (wave >> 1) * 64;
  const int qn = (wave & 1) * 64;

  f32x4 acc[4][4];
#pragma unroll
  for (int i = 0; i < 4; i++)
#pragma unroll
    for (int j = 0; j < 4; j++) acc[i][j] = (f32x4){0.f, 0.f, 0.f, 0.f};

  const u16*   Ab = (const u16*)Ap   + (gTile - aRowOff) * (long)lda;
  const float* Af = (const float*)Ap + (gTile - aRowOff) * (long)lda;
  const u16*   Bb = (const u16*)Bp   + (long)b * bBatchStride;
  const float* Bf = (const float*)Bp + (long)b * bBatchStride;

  const int lm = lane & 15;
  const int lk = (lane >> 4) * 8;

  for (int k0 = 0; k0 < K; k0 += 32) {
    if (ASRC == 0) {
      int srow = tid >> 2, scol = (tid & 3) * 8;
#pragma unroll
      for (int p = 0; p < 2; p++) {
        int r = p * 64 + srow;
        *(u16x8*)&As[r][scol] = *(const u16x8*)&Ab[(long)r * lda + k0 + scol];
      }
    } else {
      int srow = tid >> 3, scol = (tid & 7) * 4;
#pragma unroll
      for (int p = 0; p < 4; p++) {
        int r = p * 32 + srow;
        f32x4 a = *(const f32x4*)&Af[(long)r * lda + k0 + scol];
        u16x4 o;
#pragma unroll
        for (int j = 0; j < 4; j++) o[j] = f2bf(a[j]);
        *(u16x4*)&As[r][scol] = o;
      }
    }
    if (BMODE == 0) {
      if (BSRC == 0) {
        int srow = tid >> 2, scol = (tid & 3) * 8;
#pragma unroll
        for (int p = 0; p < 2; p++) {
          int r = p * 64 + srow;
          *(u16x8*)&Bs[r][scol] = *(const u16x8*)&Bb[(long)(nTile + r) * ldb + k0 + scol];
        }
      } else {
        int srow = tid >> 3, scol = (tid & 7) * 4;
#pragma unroll
        for (int p = 0; p < 4; p++) {
          int r = p * 32 + srow;
          f32x4 a = *(const f32x4*)&Bf[(long)(nTile + r) * ldb + k0 + scol];
          u16x4 o;
#pragma unroll
          for (int j = 0; j < 4; j++) o[j] = f2bf(a[j]);
          *(u16x4*)&Bs[r][scol] = o;
        }
      }
    }
    __syncthreads();

    bf16x8 af[4], bfr[4];
#pragma unroll
    for (int rt = 0; rt < 4; rt++)
      af[rt] = *(const bf16x8*)&As[qm + rt * 16 + lm][lk];
    if (BMODE == 0) {
#pragma unroll
      for (int ct = 0; ct < 4; ct++)
        bfr[ct] = *(const bf16x8*)&Bs[qn + ct * 16 + lm][lk];
    } else {
      // direct gather from fp32 V[k][n]: 8 consecutive k, fixed n (slow fallback)
#pragma unroll
      for (int ct = 0; ct < 4; ct++) {
        const float* vp = Bf + (long)(k0 + lk) * ldb + nTile + qn + ct * 16 + lm;
#pragma unroll
        for (int j = 0; j < 8; j++) bfr[ct][j] = (short)f2bf(vp[(long)j * ldb]);
      }
    }
#pragma unroll
    for (int rt = 0; rt < 4; rt++)
#pragma unroll
      for (int ct = 0; ct < 4; ct++)
        acc[rt][ct] = __builtin_amdgcn_mfma_f32_16x16x32_bf16(af[rt], bfr[ct], acc[rt][ct], 0, 0, 0);
    __syncthreads();
  }

  // epilogue: C/D layout col = lane&15, row = (lane>>4)*4 + reg
  const int lr = (lane >> 4) * 4;
#pragma unroll
  for (int rt = 0; rt < 4; rt++) {
#pragma unroll
    for (int ct = 0; ct < 4; ct++) {
      long gr = gTile + qm + rt * 16 + lr;
      int  cc = nTile + qn + ct * 16 + lm;
#pragma unroll
      for (int i = 0; i < 4; i++) {
        float v = acc[rt][ct][i] * scale;
        if (HASMASK) v += maskf[(gr + i) * (long)ldc + cc];
        if (COUT == 0)
          ((u16*)Cp)[(gr + i - cRowOff) * (long)ldc + cc] = f2bf(v);
        else
          ((float*)Cp)[(gr + i - cRowOff) * (long)ldc + cc] = v;
      }
    }
  }
}

// ---------------------------------------------------------------------------
// Row softmax in place on bf16 rows of length ncols == 2048 == 256*8
// ---------------------------------------------------------------------------
__global__ __launch_bounds__(256)
void softmax_rows(u16* __restrict__ Sbuf, int ncols)
{
  const long row = blockIdx.x;
  u16* rp = Sbuf + row * (long)ncols;
  const int tid = threadIdx.x;

  u16x8 u = *(const u16x8*)&rp[tid * 8];
  float x[8];
  float m = -3.0e38f;
#pragma unroll
  for (int i = 0; i < 8; i++) { x[i] = bf2f(u[i]); m = fmaxf(m, x[i]); }
#pragma unroll
  for (int off = 32; off; off >>= 1) m = fmaxf(m, __shfl_xor(m, off, 64));
  __shared__ float redm[4];
  if ((tid & 63) == 0) redm[tid >> 6] = m;
  __syncthreads();
  m = fmaxf(fmaxf(redm[0], redm[1]), fmaxf(redm[2], redm[3]));

  float e[8];
  float s = 0.f;
#pragma unroll
  for (int i = 0; i < 8; i++) { e[i] = exp2f((x[i] - m) * LOG2E); s += e[i]; }
#pragma unroll
  for (int off = 32; off; off >>= 1) s += __shfl_xor(s, off, 64);
  __shared__ float reds[4];
  if ((tid & 63) == 0) reds[tid >> 6] = s;
  __syncthreads();
  s = reds[0] + reds[1] + reds[2] + reds[3];

  float inv = 1.0f / s;
  u16x8 o;
#pragma unroll
  for (int i = 0; i < 8; i++) o[i] = f2bf(e[i] * inv);
  *(u16x8*)&rp[tid * 8] = o;
}

extern "C" void kernel_launch(void* const* d_in, const int* in_sizes, int n_in,
                              void* d_out, int out_size, void* d_ws, size_t ws_size,
                              hipStream_t stream)
{
  const float* Q    = (const float*)d_in[0];
  const float* Km   = (const float*)d_in[1];
  const float* V    = (const float*)d_in[2];
  const float* mask = (const float*)d_in[3];
  float* out = (float*)d_out;

  const long qsz = in_sizes[0];          // B*S*E
  const long msz = in_sizes[3];          // B*S*S
  const long E = 1024;
  const long S = (msz / qsz) * E;        // 2048
  const long B = qsz / (S * E);          // 4
  const long G = B * S;
  const float scale = 1.0f / sqrtf((float)E);

  const size_t convBytes = (size_t)(3 * qsz) * 2;   // Qb + Kb + VTb (bf16)
  const size_t rowBytes  = (size_t)S * 2;           // one bf16 score row
  char* w = (char*)d_ws;
  size_t avail = ws_size;
  const bool haveConv = (ws_size >= convBytes + 128 * rowBytes);

  u16 *Qb = nullptr, *Kb = nullptr, *VTb = nullptr;
  if (haveConv) {
    Qb  = (u16*)w;              w += (size_t)qsz * 2;
    Kb  = (u16*)w;              w += (size_t)qsz * 2;
    VTb = (u16*)w;              w += (size_t)qsz * 2;
    avail -= convBytes;
  }
  long Rmax = (long)((avail / rowBytes) / 128) * 128;
  if (Rmax > G) Rmax = G;
  if (Rmax < 128) Rmax = 128;   // assume ws >= ~0.5 MB
  u16* Sbuf = (u16*)w;

  if (haveConv) {
    cvt_f32_bf16<<<dim3((unsigned)(qsz / 2048)), 256, 0, stream>>>(Q, Qb, qsz);
    cvt_f32_bf16<<<dim3((unsigned)(qsz / 2048)), 256, 0, stream>>>(Km, Kb, qsz);
    transcvt_v<<<dim3(S / 64, E / 64, B), 256, 0, stream>>>(V, VTb, (int)S, (int)E);
  }

  for (long g0 = 0; g0 < G; g0 += Rmax) {
    const long R = (G - g0 < Rmax) ? (G - g0) : Rmax;
    if (haveConv) {
      gemm_bt_fast<1, 0><<<dim3(S / 128, R / 128), 256, 0, stream>>>(
          Qb, (int)E, 0L, Kb, (int)E, S * E,
          Sbuf, (int)S, g0, mask, (int)E, scale, g0, (int)S);
    } else {
      gemm_bt<1, 1, 0, 1, 0><<<dim3(S / 128, R / 128), 256, 0, stream>>>(
          Q, (int)E, 0L, Km, (int)E, S * E,
          Sbuf, (int)S, g0, mask, (int)E, scale, g0, (int)S);
    }
    softmax_rows<<<dim3(R), 256, 0, stream>>>(Sbuf, (int)S);
    if (haveConv) {
      gemm_bt_fast<0, 1><<<dim3(E / 128, R / 128), 256, 0, stream>>>(
          Sbuf, (int)S, g0, VTb, (int)S, E * S,
          out, (int)E, 0L, nullptr, (int)S, 1.0f, g0, (int)S);
    } else {
      gemm_bt<0, 1, 1, 0, 1><<<dim3(E / 128, R / 128), 256, 0, stream>>>(
          Sbuf, (int)S, g0, V, (int)E, S * E,
          out, (int)E, 0L, nullptr, (int)S, 1.0f, g0, (int)S);
    }
  }
}

// Round 6
// 296.611 us; speedup vs baseline: 1.0031x; 1.0031x over previous
//
#include <hip/hip_runtime.h>
#include <stdint.h>
#include <math.h>

typedef unsigned short u16;
typedef short bf16x8 __attribute__((ext_vector_type(8)));
typedef unsigned short u16x8 __attribute__((ext_vector_type(8)));
typedef unsigned short u16x4 __attribute__((ext_vector_type(4)));
typedef float f32x4 __attribute__((ext_vector_type(4)));

typedef __attribute__((address_space(1))) const void gvoid;
typedef __attribute__((address_space(3))) void lvoid;

#define LOG2E 1.4426950408889634f

__device__ __forceinline__ float bf2f(u16 u) {
  union { unsigned int i; float f; } v; v.i = ((unsigned int)u) << 16; return v.f;
}
__device__ __forceinline__ u16 f2bf(float f) {
  union { float ff; unsigned int i; } v; v.ff = f;
  unsigned int x = v.i;
  return (u16)((x + 0x7FFFu + ((x >> 16) & 1u)) >> 16);
}

// ---------------------------------------------------------------------------
// fp32 -> bf16 flat convert (n divisible by 2048 in practice; guarded anyway)
// ---------------------------------------------------------------------------
__global__ __launch_bounds__(256)
void cvt_f32_bf16(const float* __restrict__ src, u16* __restrict__ dst, long n)
{
  long i = ((long)blockIdx.x * 256 + threadIdx.x) * 8;
  if (i + 8 > n) return;
  f32x4 a = *(const f32x4*)&src[i];
  f32x4 b = *(const f32x4*)&src[i + 4];
  u16x8 o;
#pragma unroll
  for (int j = 0; j < 4; j++) { o[j] = f2bf(a[j]); o[4 + j] = f2bf(b[j]); }
  *(u16x8*)&dst[i] = o;
}

// ---------------------------------------------------------------------------
// Per-batch transpose+convert: VT[b][n][k] = (bf16)V[b][k][n]. 64x64 tiles.
// ---------------------------------------------------------------------------
__global__ __launch_bounds__(256)
void transcvt_v(const float* __restrict__ V, u16* __restrict__ VT, int S, int E)
{
  __shared__ u16 t[64][72];
  const int b = blockIdx.z;
  const float* Vb = V + (long)b * S * E;
  u16* VTb = VT + (long)b * S * E;
  const int k0 = blockIdx.x * 64, n0 = blockIdx.y * 64;
  const int tid = threadIdx.x;
#pragma unroll
  for (int p = 0; p < 2; p++) {
    int kk = p * 32 + (tid >> 3);
    int nn = (tid & 7) * 8;
    f32x4 a = *(const f32x4*)&Vb[(long)(k0 + kk) * E + n0 + nn];
    f32x4 c = *(const f32x4*)&Vb[(long)(k0 + kk) * E + n0 + nn + 4];
#pragma unroll
    for (int j = 0; j < 4; j++) { t[nn + j][kk] = f2bf(a[j]); t[nn + 4 + j][kk] = f2bf(c[j]); }
  }
  __syncthreads();
#pragma unroll
  for (int p = 0; p < 2; p++) {
    int nn = p * 32 + (tid >> 3);
    int kk = (tid & 7) * 8;
    u16x8 u;
#pragma unroll
    for (int j = 0; j < 8; j++) u[j] = t[nn][kk + j];
    *(u16x8*)&VTb[(long)(n0 + nn) * S + k0 + kk] = u;
  }
}

// ---------------------------------------------------------------------------
// FAST bf16 GEMM (BT layout), m97 structure (verified round-1 body):
//   C[g][n] = scale * sum_k A[g][k]*B[n][k] (+ mask fp32)
// 128x128 tile, BK=32, 4 waves, 4x4 16x16x32 bf16 MFMA accumulators.
// Staging via global_load_lds width=16 into LINEAR (unpadded) [128][32] LDS.
// The K-step latency (~2-3k cyc: stage+drain+barrier) is hidden by BLOCK
// co-residency (3/CU at VGPR 164) — grid must be >= ~3*256 blocks, which
// the merged launch below provides.
// ---------------------------------------------------------------------------
template<int HASMASK, int COUT>
__global__ __launch_bounds__(256, 3)
void gemm_bt_fast(const u16* __restrict__ A, int lda, long aRowOff,
                  const u16* __restrict__ B, int ldb, long bBatchStride,
                  void* __restrict__ Cp, int ldc, long cRowOff,
                  const float* __restrict__ maskf,
                  int K, float scale, long g0, int S)
{
  const int tid  = threadIdx.x;
  const int lane = tid & 63;
  const int wave = tid >> 6;
  const long gTile = g0 + (long)blockIdx.y * 128;
  const int  bidx  = (int)(gTile / S);
  const int  nTile = blockIdx.x * 128;

  __shared__ u16 As[128][32];   // linear: row stride 64B (required by global_load_lds)
  __shared__ u16 Bs[128][32];

  const u16* Ab = A + (gTile - aRowOff) * (long)lda;
  const u16* Bb = B + (long)bidx * bBatchStride + (long)nTile * ldb;

  const int qm = (wave >> 1) * 64;
  const int qn = (wave & 1) * 64;
  const int lm  = lane & 15;          // m/n index within 16x16 fragment
  const int lkB = (lane >> 4) * 16;   // byte offset of k-slice within LDS row

  // staging decomposition: each wave covers two 1024B chunks (16 rows each);
  // lane l writes LDS byte (chunk*1024 + l*16) -> row = chunk*16 + l/4,
  // col(u16) = (l&3)*8. Global src must match that (row,col).
  const int sr = lane >> 2;
  const int sc = (lane & 3) * 8;

  f32x4 acc[4][4];
#pragma unroll
  for (int i = 0; i < 4; i++)
#pragma unroll
    for (int j = 0; j < 4; j++) acc[i][j] = (f32x4){0.f, 0.f, 0.f, 0.f};

  for (int k0 = 0; k0 < K; k0 += 32) {
#pragma unroll
    for (int p = 0; p < 2; p++) {
      const int chunk = wave * 2 + p;        // 0..7, wave-uniform
      const int r = chunk * 16 + sr;
      __builtin_amdgcn_global_load_lds(
          (gvoid*)&Ab[(long)r * lda + k0 + sc],
          (lvoid*)((char*)&As[0][0] + chunk * 1024),
          16, 0, 0);
      __builtin_amdgcn_global_load_lds(
          (gvoid*)&Bb[(long)r * ldb + k0 + sc],
          (lvoid*)((char*)&Bs[0][0] + chunk * 1024),
          16, 0, 0);
    }
    __syncthreads();

    bf16x8 af[4], bfr[4];
#pragma unroll
    for (int rt = 0; rt < 4; rt++)
      af[rt] = *(const bf16x8*)((const char*)&As[qm + rt * 16 + lm][0] + lkB);
#pragma unroll
    for (int ct = 0; ct < 4; ct++)
      bfr[ct] = *(const bf16x8*)((const char*)&Bs[qn + ct * 16 + lm][0] + lkB);

#pragma unroll
    for (int rt = 0; rt < 4; rt++)
#pragma unroll
      for (int ct = 0; ct < 4; ct++)
        acc[rt][ct] = __builtin_amdgcn_mfma_f32_16x16x32_bf16(af[rt], bfr[ct], acc[rt][ct], 0, 0, 0);
    __syncthreads();
  }

  // epilogue: C/D layout col = lane&15, row = (lane>>4)*4 + reg
  const int lr = (lane >> 4) * 4;
#pragma unroll
  for (int rt = 0; rt < 4; rt++) {
#pragma unroll
    for (int ct = 0; ct < 4; ct++) {
      long gr = gTile + qm + rt * 16 + lr;
      int  cc = nTile + qn + ct * 16 + lm;
#pragma unroll
      for (int i = 0; i < 4; i++) {
        float v = acc[rt][ct][i] * scale;
        if (HASMASK) v += maskf[(gr + i) * (long)ldc + cc];
        if (COUT == 0)
          ((u16*)Cp)[(gr + i - cRowOff) * (long)ldc + cc] = f2bf(v);
        else
          ((float*)Cp)[(gr + i - cRowOff) * (long)ldc + cc] = v;
      }
    }
  }
}

// ---------------------------------------------------------------------------
// GEMM (BT layout) — generic fallback (fp32 sources, no-workspace path).
// ---------------------------------------------------------------------------
template<int ASRC, int BSRC, int BMODE, int HASMASK, int COUT>
__global__ __launch_bounds__(256, 2)
void gemm_bt(const void* __restrict__ Ap, int lda, long aRowOff,
             const void* __restrict__ Bp, int ldb, long bBatchStride,
             void* __restrict__ Cp, int ldc, long cRowOff,
             const float* __restrict__ maskf,
             int K, float scale, long g0, int S)
{
  const int tid  = threadIdx.x;
  const int lane = tid & 63;
  const int wave = tid >> 6;
  const long gTile = g0 + (long)blockIdx.y * 128;
  const int  b     = (int)(gTile / S);
  const int  nTile = blockIdx.x * 128;

  __shared__ u16 As[128][40];   // +8 pad keeps 16B row alignment
  __shared__ u16 Bs[128][40];

  const int qm = (wave >> 1) * 64;
  const int qn = (wave & 1) * 64;

  f32x4 acc[4][4];
#pragma unroll
  for (int i = 0; i < 4; i++)
#pragma unroll
    for (int j = 0; j < 4; j++) acc[i][j] = (f32x4){0.f, 0.f, 0.f, 0.f};

  const u16*   Ab = (const u16*)Ap   + (gTile - aRowOff) * (long)lda;
  const float* Af = (const float*)Ap + (gTile - aRowOff) * (long)lda;
  const u16*   Bb = (const u16*)Bp   + (long)b * bBatchStride;
  const float* Bf = (const float*)Bp + (long)b * bBatchStride;

  const int lm = lane & 15;
  const int lk = (lane >> 4) * 8;

  for (int k0 = 0; k0 < K; k0 += 32) {
    if (ASRC == 0) {
      int srow = tid >> 2, scol = (tid & 3) * 8;
#pragma unroll
      for (int p = 0; p < 2; p++) {
        int r = p * 64 + srow;
        *(u16x8*)&As[r][scol] = *(const u16x8*)&Ab[(long)r * lda + k0 + scol];
      }
    } else {
      int srow = tid >> 3, scol = (tid & 7) * 4;
#pragma unroll
      for (int p = 0; p < 4; p++) {
        int r = p * 32 + srow;
        f32x4 a = *(const f32x4*)&Af[(long)r * lda + k0 + scol];
        u16x4 o;
#pragma unroll
        for (int j = 0; j < 4; j++) o[j] = f2bf(a[j]);
        *(u16x4*)&As[r][scol] = o;
      }
    }
    if (BMODE == 0) {
      if (BSRC == 0) {
        int srow = tid >> 2, scol = (tid & 3) * 8;
#pragma unroll
        for (int p = 0; p < 2; p++) {
          int r = p * 64 + srow;
          *(u16x8*)&Bs[r][scol] = *(const u16x8*)&Bb[(long)(nTile + r) * ldb + k0 + scol];
        }
      } else {
        int srow = tid >> 3, scol = (tid & 7) * 4;
#pragma unroll
        for (int p = 0; p < 4; p++) {
          int r = p * 32 + srow;
          f32x4 a = *(const f32x4*)&Bf[(long)(nTile + r) * ldb + k0 + scol];
          u16x4 o;
#pragma unroll
          for (int j = 0; j < 4; j++) o[j] = f2bf(a[j]);
          *(u16x4*)&Bs[r][scol] = o;
        }
      }
    }
    __syncthreads();

    bf16x8 af[4], bfr[4];
#pragma unroll
    for (int rt = 0; rt < 4; rt++)
      af[rt] = *(const bf16x8*)&As[qm + rt * 16 + lm][lk];
    if (BMODE == 0) {
#pragma unroll
      for (int ct = 0; ct < 4; ct++)
        bfr[ct] = *(const bf16x8*)&Bs[qn + ct * 16 + lm][lk];
    } else {
      // direct gather from fp32 V[k][n]: 8 consecutive k, fixed n (slow fallback)
#pragma unroll
      for (int ct = 0; ct < 4; ct++) {
        const float* vp = Bf + (long)(k0 + lk) * ldb + nTile + qn + ct * 16 + lm;
#pragma unroll
        for (int j = 0; j < 8; j++) bfr[ct][j] = (short)f2bf(vp[(long)j * ldb]);
      }
    }
#pragma unroll
    for (int rt = 0; rt < 4; rt++)
#pragma unroll
      for (int ct = 0; ct < 4; ct++)
        acc[rt][ct] = __builtin_amdgcn_mfma_f32_16x16x32_bf16(af[rt], bfr[ct], acc[rt][ct], 0, 0, 0);
    __syncthreads();
  }

  // epilogue: C/D layout col = lane&15, row = (lane>>4)*4 + reg
  const int lr = (lane >> 4) * 4;
#pragma unroll
  for (int rt = 0; rt < 4; rt++) {
#pragma unroll
    for (int ct = 0; ct < 4; ct++) {
      long gr = gTile + qm + rt * 16 + lr;
      int  cc = nTile + qn + ct * 16 + lm;
#pragma unroll
      for (int i = 0; i < 4; i++) {
        float v = acc[rt][ct][i] * scale;
        if (HASMASK) v += maskf[(gr + i) * (long)ldc + cc];
        if (COUT == 0)
          ((u16*)Cp)[(gr + i - cRowOff) * (long)ldc + cc] = f2bf(v);
        else
          ((float*)Cp)[(gr + i - cRowOff) * (long)ldc + cc] = v;
      }
    }
  }
}

// ---------------------------------------------------------------------------
// Row softmax in place on bf16 rows of length ncols == 2048 == 256*8
// ---------------------------------------------------------------------------
__global__ __launch_bounds__(256)
void softmax_rows(u16* __restrict__ Sbuf, int ncols)
{
  const long row = blockIdx.x;
  u16* rp = Sbuf + row * (long)ncols;
  const int tid = threadIdx.x;

  u16x8 u = *(const u16x8*)&rp[tid * 8];
  float x[8];
  float m = -3.0e38f;
#pragma unroll
  for (int i = 0; i < 8; i++) { x[i] = bf2f(u[i]); m = fmaxf(m, x[i]); }
#pragma unroll
  for (int off = 32; off; off >>= 1) m = fmaxf(m, __shfl_xor(m, off, 64));
  __shared__ float redm[4];
  if ((tid & 63) == 0) redm[tid >> 6] = m;
  __syncthreads();
  m = fmaxf(fmaxf(redm[0], redm[1]), fmaxf(redm[2], redm[3]));

  float e[8];
  float s = 0.f;
#pragma unroll
  for (int i = 0; i < 8; i++) { e[i] = exp2f((x[i] - m) * LOG2E); s += e[i]; }
#pragma unroll
  for (int off = 32; off; off >>= 1) s += __shfl_xor(s, off, 64);
  __shared__ float reds[4];
  if ((tid & 63) == 0) reds[tid >> 6] = s;
  __syncthreads();
  s = reds[0] + reds[1] + reds[2] + reds[3];

  float inv = 1.0f / s;
  u16x8 o;
#pragma unroll
  for (int i = 0; i < 8; i++) o[i] = f2bf(e[i] * inv);
  *(u16x8*)&rp[tid * 8] = o;
}

extern "C" void kernel_launch(void* const* d_in, const int* in_sizes, int n_in,
                              void* d_out, int out_size, void* d_ws, size_t ws_size,
                              hipStream_t stream)
{
  const float* Q    = (const float*)d_in[0];
  const float* Km   = (const float*)d_in[1];
  const float* V    = (const float*)d_in[2];
  const float* mask = (const float*)d_in[3];
  float* out = (float*)d_out;

  const long qsz = in_sizes[0];          // B*S*E
  const long msz = in_sizes[3];          // B*S*S
  const long E = 1024;
  const long S = (msz / qsz) * E;        // 2048
  const long B = qsz / (S * E);          // 4
  const long G = B * S;
  const float scale = 1.0f / sqrtf((float)E);

  // ---- MERGED single-pass path: Qb|Kb|Sbuf, VTb aliases Qb after QK^T ----
  // Peak ws need = 2*qsz*2 (Qb+Kb) + G*S*2 (full Sbuf). VTb (qsz*2) reuses
  // Qb's slot once QK^T has consumed Qb. Doubles both GEMM grids:
  // QK^T 1024 blocks (3 resident/CU), PV 512 — the K-step latency of the
  // m97 structure is hidden by block co-residency, which the old 2-chunk
  // launch (512/256 blocks) could not supply.
  const size_t mergedBytes = (size_t)(2 * qsz) * 2 + (size_t)G * S * 2;
  if (ws_size >= mergedBytes) {
    char* w = (char*)d_ws;
    u16* Qb   = (u16*)w;
    u16* Kb   = (u16*)(w + (size_t)qsz * 2);
    u16* Sbuf = (u16*)(w + (size_t)(2 * qsz) * 2);
    u16* VTb  = Qb;   // alias: written only after QK^T is done with Qb

    cvt_f32_bf16<<<dim3((unsigned)(qsz / 2048)), 256, 0, stream>>>(Q, Qb, qsz);
    cvt_f32_bf16<<<dim3((unsigned)(qsz / 2048)), 256, 0, stream>>>(Km, Kb, qsz);

    gemm_bt_fast<1, 0><<<dim3(S / 128, G / 128), 256, 0, stream>>>(
        Qb, (int)E, 0L, Kb, (int)E, S * E,
        Sbuf, (int)S, 0L, mask, (int)E, scale, 0L, (int)S);

    softmax_rows<<<dim3((unsigned)G), 256, 0, stream>>>(Sbuf, (int)S);

    transcvt_v<<<dim3(S / 64, E / 64, B), 256, 0, stream>>>(V, VTb, (int)S, (int)E);

    gemm_bt_fast<0, 1><<<dim3(E / 128, G / 128), 256, 0, stream>>>(
        Sbuf, (int)S, 0L, VTb, (int)S, E * S,
        out, (int)E, 0L, nullptr, (int)S, 1.0f, 0L, (int)S);
    return;
  }

  // ---- fallback: chunked path (round-1 verified) ----
  const size_t convBytes = (size_t)(3 * qsz) * 2;   // Qb + Kb + VTb (bf16)
  const size_t rowBytes  = (size_t)S * 2;           // one bf16 score row
  char* w = (char*)d_ws;
  size_t avail = ws_size;
  const bool haveConv = (ws_size >= convBytes + 128 * rowBytes);

  u16 *Qb = nullptr, *Kb = nullptr, *VTb = nullptr;
  if (haveConv) {
    Qb  = (u16*)w;              w += (size_t)qsz * 2;
    Kb  = (u16*)w;              w += (size_t)qsz * 2;
    VTb = (u16*)w;              w += (size_t)qsz * 2;
    avail -= convBytes;
  }
  long Rmax = (long)((avail / rowBytes) / 128) * 128;
  if (Rmax > G) Rmax = G;
  if (Rmax < 128) Rmax = 128;   // assume ws >= ~0.5 MB
  u16* Sbuf = (u16*)w;

  if (haveConv) {
    cvt_f32_bf16<<<dim3((unsigned)(qsz / 2048)), 256, 0, stream>>>(Q, Qb, qsz);
    cvt_f32_bf16<<<dim3((unsigned)(qsz / 2048)), 256, 0, stream>>>(Km, Kb, qsz);
    transcvt_v<<<dim3(S / 64, E / 64, B), 256, 0, stream>>>(V, VTb, (int)S, (int)E);
  }

  for (long g0 = 0; g0 < G; g0 += Rmax) {
    const long R = (G - g0 < Rmax) ? (G - g0) : Rmax;
    if (haveConv) {
      gemm_bt_fast<1, 0><<<dim3(S / 128, R / 128), 256, 0, stream>>>(
          Qb, (int)E, 0L, Kb, (int)E, S * E,
          Sbuf, (int)S, g0, mask, (int)E, scale, g0, (int)S);
    } else {
      gemm_bt<1, 1, 0, 1, 0><<<dim3(S / 128, R / 128), 256, 0, stream>>>(
          Q, (int)E, 0L, Km, (int)E, S * E,
          Sbuf, (int)S, g0, mask, (int)E, scale, g0, (int)S);
    }
    softmax_rows<<<dim3(R), 256, 0, stream>>>(Sbuf, (int)S);
    if (haveConv) {
      gemm_bt_fast<0, 1><<<dim3(E / 128, R / 128), 256, 0, stream>>>(
          Sbuf, (int)S, g0, VTb, (int)S, E * S,
          out, (int)E, 0L, nullptr, (int)S, 1.0f, g0, (int)S);
    } else {
      gemm_bt<0, 1, 1, 0, 1><<<dim3(E / 128, R / 128), 256, 0, stream>>>(
          Sbuf, (int)S, g0, V, (int)E, S * E,
          out, (int)E, 0L, nullptr, (int)S, 1.0f, g0, (int)S);
    }
  }
}

// Round 7
// 279.218 us; speedup vs baseline: 1.0655x; 1.0623x over previous
//
#include <hip/hip_runtime.h>
#include <stdint.h>
#include <math.h>

typedef unsigned short u16;
typedef short bf16x8 __attribute__((ext_vector_type(8)));
typedef unsigned short u16x8 __attribute__((ext_vector_type(8)));
typedef unsigned short u16x4 __attribute__((ext_vector_type(4)));
typedef float f32x4 __attribute__((ext_vector_type(4)));

typedef __attribute__((address_space(1))) const void gvoid;
typedef __attribute__((address_space(3))) void lvoid;

#define LOG2E 1.4426950408889634f

__device__ __forceinline__ float bf2f(u16 u) {
  union { unsigned int i; float f; } v; v.i = ((unsigned int)u) << 16; return v.f;
}
__device__ __forceinline__ u16 f2bf(float f) {
  union { float ff; unsigned int i; } v; v.ff = f;
  unsigned int x = v.i;
  return (u16)((x + 0x7FFFu + ((x >> 16) & 1u)) >> 16);
}

// ---------------------------------------------------------------------------
// fp32 -> bf16 flat convert of TWO buffers in one dispatch (Q then K).
// n elements each; n divisible by 2048.
// ---------------------------------------------------------------------------
__global__ __launch_bounds__(256)
void cvt2_f32_bf16(const float* __restrict__ s0, u16* __restrict__ d0,
                   const float* __restrict__ s1, u16* __restrict__ d1, long n)
{
  const long nb = n / 2048;                  // blocks per buffer
  const float* src = (blockIdx.x < nb) ? s0 : s1;
  u16* dst         = (blockIdx.x < nb) ? d0 : d1;
  const long bid   = (blockIdx.x < nb) ? blockIdx.x : (blockIdx.x - nb);
  long i = (bid * 256 + threadIdx.x) * 8;
  if (i + 8 > n) return;
  f32x4 a = *(const f32x4*)&src[i];
  f32x4 b = *(const f32x4*)&src[i + 4];
  u16x8 o;
#pragma unroll
  for (int j = 0; j < 4; j++) { o[j] = f2bf(a[j]); o[4 + j] = f2bf(b[j]); }
  *(u16x8*)&dst[i] = o;
}

__global__ __launch_bounds__(256)
void cvt_f32_bf16(const float* __restrict__ src, u16* __restrict__ dst, long n)
{
  long i = ((long)blockIdx.x * 256 + threadIdx.x) * 8;
  if (i + 8 > n) return;
  f32x4 a = *(const f32x4*)&src[i];
  f32x4 b = *(const f32x4*)&src[i + 4];
  u16x8 o;
#pragma unroll
  for (int j = 0; j < 4; j++) { o[j] = f2bf(a[j]); o[4 + j] = f2bf(b[j]); }
  *(u16x8*)&dst[i] = o;
}

// ---------------------------------------------------------------------------
// Per-batch transpose+convert: VT[b][n][k] = (bf16)V[b][k][n]. 64x64 tiles.
// ---------------------------------------------------------------------------
__global__ __launch_bounds__(256)
void transcvt_v(const float* __restrict__ V, u16* __restrict__ VT, int S, int E)
{
  __shared__ u16 t[64][72];
  const int b = blockIdx.z;
  const float* Vb = V + (long)b * S * E;
  u16* VTb = VT + (long)b * S * E;
  const int k0 = blockIdx.x * 64, n0 = blockIdx.y * 64;
  const int tid = threadIdx.x;
#pragma unroll
  for (int p = 0; p < 2; p++) {
    int kk = p * 32 + (tid >> 3);
    int nn = (tid & 7) * 8;
    f32x4 a = *(const f32x4*)&Vb[(long)(k0 + kk) * E + n0 + nn];
    f32x4 c = *(const f32x4*)&Vb[(long)(k0 + kk) * E + n0 + nn + 4];
#pragma unroll
    for (int j = 0; j < 4; j++) { t[nn + j][kk] = f2bf(a[j]); t[nn + 4 + j][kk] = f2bf(c[j]); }
  }
  __syncthreads();
#pragma unroll
  for (int p = 0; p < 2; p++) {
    int nn = p * 32 + (tid >> 3);
    int kk = (tid & 7) * 8;
    u16x8 u;
#pragma unroll
    for (int j = 0; j < 8; j++) u[j] = t[nn][kk + j];
    *(u16x8*)&VTb[(long)(n0 + nn) * S + k0 + kk] = u;
  }
}

// ---------------------------------------------------------------------------
// FAST bf16 GEMM (BT layout), m97 structure (verified round-1 body):
//   C[g][n] = scale * sum_k A[g][k]*B[n][k] (+ mask fp32 if HASMASK)
// 128x128 tile, BK=32, 4 waves, 4x4 16x16x32 bf16 MFMA accumulators.
// Staging via global_load_lds width=16 into LINEAR (unpadded) [128][32] LDS.
// In the merged path HASMASK=0: mask add is fused into softmax instead,
// removing the 64 MB fp32 serial epilogue read (44% of QK^T HBM traffic).
// ---------------------------------------------------------------------------
template<int HASMASK, int COUT>
__global__ __launch_bounds__(256, 3)
void gemm_bt_fast(const u16* __restrict__ A, int lda, long aRowOff,
                  const u16* __restrict__ B, int ldb, long bBatchStride,
                  void* __restrict__ Cp, int ldc, long cRowOff,
                  const float* __restrict__ maskf,
                  int K, float scale, long g0, int S)
{
  const int tid  = threadIdx.x;
  const int lane = tid & 63;
  const int wave = tid >> 6;
  const long gTile = g0 + (long)blockIdx.y * 128;
  const int  bidx  = (int)(gTile / S);
  const int  nTile = blockIdx.x * 128;

  __shared__ u16 As[128][32];   // linear: row stride 64B (required by global_load_lds)
  __shared__ u16 Bs[128][32];

  const u16* Ab = A + (gTile - aRowOff) * (long)lda;
  const u16* Bb = B + (long)bidx * bBatchStride + (long)nTile * ldb;

  const int qm = (wave >> 1) * 64;
  const int qn = (wave & 1) * 64;
  const int lm  = lane & 15;          // m/n index within 16x16 fragment
  const int lkB = (lane >> 4) * 16;   // byte offset of k-slice within LDS row

  const int sr = lane >> 2;
  const int sc = (lane & 3) * 8;

  f32x4 acc[4][4];
#pragma unroll
  for (int i = 0; i < 4; i++)
#pragma unroll
    for (int j = 0; j < 4; j++) acc[i][j] = (f32x4){0.f, 0.f, 0.f, 0.f};

  for (int k0 = 0; k0 < K; k0 += 32) {
#pragma unroll
    for (int p = 0; p < 2; p++) {
      const int chunk = wave * 2 + p;        // 0..7, wave-uniform
      const int r = chunk * 16 + sr;
      __builtin_amdgcn_global_load_lds(
          (gvoid*)&Ab[(long)r * lda + k0 + sc],
          (lvoid*)((char*)&As[0][0] + chunk * 1024),
          16, 0, 0);
      __builtin_amdgcn_global_load_lds(
          (gvoid*)&Bb[(long)r * ldb + k0 + sc],
          (lvoid*)((char*)&Bs[0][0] + chunk * 1024),
          16, 0, 0);
    }
    __syncthreads();

    bf16x8 af[4], bfr[4];
#pragma unroll
    for (int rt = 0; rt < 4; rt++)
      af[rt] = *(const bf16x8*)((const char*)&As[qm + rt * 16 + lm][0] + lkB);
#pragma unroll
    for (int ct = 0; ct < 4; ct++)
      bfr[ct] = *(const bf16x8*)((const char*)&Bs[qn + ct * 16 + lm][0] + lkB);

#pragma unroll
    for (int rt = 0; rt < 4; rt++)
#pragma unroll
      for (int ct = 0; ct < 4; ct++)
        acc[rt][ct] = __builtin_amdgcn_mfma_f32_16x16x32_bf16(af[rt], bfr[ct], acc[rt][ct], 0, 0, 0);
    __syncthreads();
  }

  // epilogue: C/D layout col = lane&15, row = (lane>>4)*4 + reg
  const int lr = (lane >> 4) * 4;
#pragma unroll
  for (int rt = 0; rt < 4; rt++) {
#pragma unroll
    for (int ct = 0; ct < 4; ct++) {
      long gr = gTile + qm + rt * 16 + lr;
      int  cc = nTile + qn + ct * 16 + lm;
#pragma unroll
      for (int i = 0; i < 4; i++) {
        float v = acc[rt][ct][i] * scale;
        if (HASMASK) v += maskf[(gr + i) * (long)ldc + cc];
        if (COUT == 0)
          ((u16*)Cp)[(gr + i - cRowOff) * (long)ldc + cc] = f2bf(v);
        else
          ((float*)Cp)[(gr + i - cRowOff) * (long)ldc + cc] = v;
      }
    }
  }
}

// ---------------------------------------------------------------------------
// GEMM (BT layout) — generic fallback (fp32 sources, no-workspace path).
// ---------------------------------------------------------------------------
template<int ASRC, int BSRC, int BMODE, int HASMASK, int COUT>
__global__ __launch_bounds__(256, 2)
void gemm_bt(const void* __restrict__ Ap, int lda, long aRowOff,
             const void* __restrict__ Bp, int ldb, long bBatchStride,
             void* __restrict__ Cp, int ldc, long cRowOff,
             const float* __restrict__ maskf,
             int K, float scale, long g0, int S)
{
  const int tid  = threadIdx.x;
  const int lane = tid & 63;
  const int wave = tid >> 6;
  const long gTile = g0 + (long)blockIdx.y * 128;
  const int  b     = (int)(gTile / S);
  const int  nTile = blockIdx.x * 128;

  __shared__ u16 As[128][40];
  __shared__ u16 Bs[128][40];

  const int qm = (wave >> 1) * 64;
  const int qn = (wave & 1) * 64;

  f32x4 acc[4][4];
#pragma unroll
  for (int i = 0; i < 4; i++)
#pragma unroll
    for (int j = 0; j < 4; j++) acc[i][j] = (f32x4){0.f, 0.f, 0.f, 0.f};

  const u16*   Ab = (const u16*)Ap   + (gTile - aRowOff) * (long)lda;
  const float* Af = (const float*)Ap + (gTile - aRowOff) * (long)lda;
  const u16*   Bb = (const u16*)Bp   + (long)b * bBatchStride;
  const float* Bf = (const float*)Bp + (long)b * bBatchStride;

  const int lm = lane & 15;
  const int lk = (lane >> 4) * 8;

  for (int k0 = 0; k0 < K; k0 += 32) {
    if (ASRC == 0) {
      int srow = tid >> 2, scol = (tid & 3) * 8;
#pragma unroll
      for (int p = 0; p < 2; p++) {
        int r = p * 64 + srow;
        *(u16x8*)&As[r][scol] = *(const u16x8*)&Ab[(long)r * lda + k0 + scol];
      }
    } else {
      int srow = tid >> 3, scol = (tid & 7) * 4;
#pragma unroll
      for (int p = 0; p < 4; p++) {
        int r = p * 32 + srow;
        f32x4 a = *(const f32x4*)&Af[(long)r * lda + k0 + scol];
        u16x4 o;
#pragma unroll
        for (int j = 0; j < 4; j++) o[j] = f2bf(a[j]);
        *(u16x4*)&As[r][scol] = o;
      }
    }
    if (BMODE == 0) {
      if (BSRC == 0) {
        int srow = tid >> 2, scol = (tid & 3) * 8;
#pragma unroll
        for (int p = 0; p < 2; p++) {
          int r = p * 64 + srow;
          *(u16x8*)&Bs[r][scol] = *(const u16x8*)&Bb[(long)(nTile + r) * ldb + k0 + scol];
        }
      } else {
        int srow = tid >> 3, scol = (tid & 7) * 4;
#pragma unroll
        for (int p = 0; p < 4; p++) {
          int r = p * 32 + srow;
          f32x4 a = *(const f32x4*)&Bf[(long)(nTile + r) * ldb + k0 + scol];
          u16x4 o;
#pragma unroll
          for (int j = 0; j < 4; j++) o[j] = f2bf(a[j]);
          *(u16x4*)&Bs[r][scol] = o;
        }
      }
    }
    __syncthreads();

    bf16x8 af[4], bfr[4];
#pragma unroll
    for (int rt = 0; rt < 4; rt++)
      af[rt] = *(const bf16x8*)&As[qm + rt * 16 + lm][lk];
    if (BMODE == 0) {
#pragma unroll
      for (int ct = 0; ct < 4; ct++)
        bfr[ct] = *(const bf16x8*)&Bs[qn + ct * 16 + lm][lk];
    } else {
#pragma unroll
      for (int ct = 0; ct < 4; ct++) {
        const float* vp = Bf + (long)(k0 + lk) * ldb + nTile + qn + ct * 16 + lm;
#pragma unroll
        for (int j = 0; j < 8; j++) bfr[ct][j] = (short)f2bf(vp[(long)j * ldb]);
      }
    }
#pragma unroll
    for (int rt = 0; rt < 4; rt++)
#pragma unroll
      for (int ct = 0; ct < 4; ct++)
        acc[rt][ct] = __builtin_amdgcn_mfma_f32_16x16x32_bf16(af[rt], bfr[ct], acc[rt][ct], 0, 0, 0);
    __syncthreads();
  }

  const int lr = (lane >> 4) * 4;
#pragma unroll
  for (int rt = 0; rt < 4; rt++) {
#pragma unroll
    for (int ct = 0; ct < 4; ct++) {
      long gr = gTile + qm + rt * 16 + lr;
      int  cc = nTile + qn + ct * 16 + lm;
#pragma unroll
      for (int i = 0; i < 4; i++) {
        float v = acc[rt][ct][i] * scale;
        if (HASMASK) v += maskf[(gr + i) * (long)ldc + cc];
        if (COUT == 0)
          ((u16*)Cp)[(gr + i - cRowOff) * (long)ldc + cc] = f2bf(v);
        else
          ((float*)Cp)[(gr + i - cRowOff) * (long)ldc + cc] = v;
      }
    }
  }
}

// ---------------------------------------------------------------------------
// Row softmax in place on bf16 rows of length ncols == 2048 == 256*8.
// HASM=1: add fp32 mask row (coalesced f32x4) before softmax — fusion of the
// reference's  softmax(qk*scale + mask).
// ---------------------------------------------------------------------------
template<int HASM>
__global__ __launch_bounds__(256)
void softmax_rows(u16* __restrict__ Sbuf, const float* __restrict__ maskf, int ncols)
{
  const long row = blockIdx.x;
  u16* rp = Sbuf + row * (long)ncols;
  const int tid = threadIdx.x;

  u16x8 u = *(const u16x8*)&rp[tid * 8];
  float x[8];
  if (HASM) {
    const float* mp = maskf + row * (long)ncols + tid * 8;
    f32x4 ma = *(const f32x4*)&mp[0];
    f32x4 mb = *(const f32x4*)&mp[4];
#pragma unroll
    for (int i = 0; i < 4; i++) { x[i] = bf2f(u[i]) + ma[i]; x[4 + i] = bf2f(u[4 + i]) + mb[i]; }
  } else {
#pragma unroll
    for (int i = 0; i < 8; i++) x[i] = bf2f(u[i]);
  }
  float m = -3.0e38f;
#pragma unroll
  for (int i = 0; i < 8; i++) m = fmaxf(m, x[i]);
#pragma unroll
  for (int off = 32; off; off >>= 1) m = fmaxf(m, __shfl_xor(m, off, 64));
  __shared__ float redm[4];
  if ((tid & 63) == 0) redm[tid >> 6] = m;
  __syncthreads();
  m = fmaxf(fmaxf(redm[0], redm[1]), fmaxf(redm[2], redm[3]));

  float e[8];
  float s = 0.f;
#pragma unroll
  for (int i = 0; i < 8; i++) { e[i] = exp2f((x[i] - m) * LOG2E); s += e[i]; }
#pragma unroll
  for (int off = 32; off; off >>= 1) s += __shfl_xor(s, off, 64);
  __shared__ float reds[4];
  if ((tid & 63) == 0) reds[tid >> 6] = s;
  __syncthreads();
  s = reds[0] + reds[1] + reds[2] + reds[3];

  float inv = 1.0f / s;
  u16x8 o;
#pragma unroll
  for (int i = 0; i < 8; i++) o[i] = f2bf(e[i] * inv);
  *(u16x8*)&rp[tid * 8] = o;
}

extern "C" void kernel_launch(void* const* d_in, const int* in_sizes, int n_in,
                              void* d_out, int out_size, void* d_ws, size_t ws_size,
                              hipStream_t stream)
{
  const float* Q    = (const float*)d_in[0];
  const float* Km   = (const float*)d_in[1];
  const float* V    = (const float*)d_in[2];
  const float* mask = (const float*)d_in[3];
  float* out = (float*)d_out;

  const long qsz = in_sizes[0];          // B*S*E
  const long msz = in_sizes[3];          // B*S*S
  const long E = 1024;
  const long S = (msz / qsz) * E;        // 2048
  const long B = qsz / (S * E);          // 4
  const long G = B * S;
  const float scale = 1.0f / sqrtf((float)E);

  // ---- MERGED single-pass path: Qb|Kb|Sbuf, VTb aliases Qb after QK^T ----
  // Mask is fused into softmax (not the GEMM epilogue): removes the 64 MB
  // fp32 serial epilogue read from QK^T (~44% of its HBM traffic).
  const size_t mergedBytes = (size_t)(2 * qsz) * 2 + (size_t)G * S * 2;
  if (ws_size >= mergedBytes) {
    char* w = (char*)d_ws;
    u16* Qb   = (u16*)w;
    u16* Kb   = (u16*)(w + (size_t)qsz * 2);
    u16* Sbuf = (u16*)(w + (size_t)(2 * qsz) * 2);
    u16* VTb  = Qb;   // alias: written only after QK^T is done with Qb

    cvt2_f32_bf16<<<dim3((unsigned)(2 * qsz / 2048)), 256, 0, stream>>>(
        Q, Qb, Km, Kb, qsz);

    gemm_bt_fast<0, 0><<<dim3(S / 128, G / 128), 256, 0, stream>>>(
        Qb, (int)E, 0L, Kb, (int)E, S * E,
        Sbuf, (int)S, 0L, nullptr, (int)E, scale, 0L, (int)S);

    softmax_rows<1><<<dim3((unsigned)G), 256, 0, stream>>>(Sbuf, mask, (int)S);

    transcvt_v<<<dim3(S / 64, E / 64, B), 256, 0, stream>>>(V, VTb, (int)S, (int)E);

    gemm_bt_fast<0, 1><<<dim3(E / 128, G / 128), 256, 0, stream>>>(
        Sbuf, (int)S, 0L, VTb, (int)S, E * S,
        out, (int)E, 0L, nullptr, (int)S, 1.0f, 0L, (int)S);
    return;
  }

  // ---- fallback: chunked path (round-1 verified) ----
  const size_t convBytes = (size_t)(3 * qsz) * 2;   // Qb + Kb + VTb (bf16)
  const size_t rowBytes  = (size_t)S * 2;           // one bf16 score row
  char* w = (char*)d_ws;
  size_t avail = ws_size;
  const bool haveConv = (ws_size >= convBytes + 128 * rowBytes);

  u16 *Qb = nullptr, *Kb = nullptr, *VTb = nullptr;
  if (haveConv) {
    Qb  = (u16*)w;              w += (size_t)qsz * 2;
    Kb  = (u16*)w;              w += (size_t)qsz * 2;
    VTb = (u16*)w;              w += (size_t)qsz * 2;
    avail -= convBytes;
  }
  long Rmax = (long)((avail / rowBytes) / 128) * 128;
  if (Rmax > G) Rmax = G;
  if (Rmax < 128) Rmax = 128;
  u16* Sbuf = (u16*)w;

  if (haveConv) {
    cvt_f32_bf16<<<dim3((unsigned)(qsz / 2048)), 256, 0, stream>>>(Q, Qb, qsz);
    cvt_f32_bf16<<<dim3((unsigned)(qsz / 2048)), 256, 0, stream>>>(Km, Kb, qsz);
    transcvt_v<<<dim3(S / 64, E / 64, B), 256, 0, stream>>>(V, VTb, (int)S, (int)E);
  }

  for (long g0 = 0; g0 < G; g0 += Rmax) {
    const long R = (G - g0 < Rmax) ? (G - g0) : Rmax;
    if (haveConv) {
      gemm_bt_fast<1, 0><<<dim3(S / 128, R / 128), 256, 0, stream>>>(
          Qb, (int)E, 0L, Kb, (int)E, S * E,
          Sbuf, (int)S, g0, mask, (int)E, scale, g0, (int)S);
    } else {
      gemm_bt<1, 1, 0, 1, 0><<<dim3(S / 128, R / 128), 256, 0, stream>>>(
          Q, (int)E, 0L, Km, (int)E, S * E,
          Sbuf, (int)S, g0, mask, (int)E, scale, g0, (int)S);
    }
    softmax_rows<0><<<dim3(R), 256, 0, stream>>>(Sbuf, nullptr, (int)S);
    if (haveConv) {
      gemm_bt_fast<0, 1><<<dim3(E / 128, R / 128), 256, 0, stream>>>(
          Sbuf, (int)S, g0, VTb, (int)S, E * S,
          out, (int)E, 0L, nullptr, (int)S, 1.0f, g0, (int)S);
    } else {
      gemm_bt<0, 1, 1, 0, 1><<<dim3(E / 128, R / 128), 256, 0, stream>>>(
          Sbuf, (int)S, g0, V, (int)E, S * E,
          out, (int)E, 0L, nullptr, (int)S, 1.0f, g0, (int)S);
    }
  }
}